// Round 1
// baseline (424.642 us; speedup 1.0000x reference)
//
#include <hip/hip_runtime.h>
#include <math.h>

#define NT 128        // trees
#define NB 1024       // batch
#define ND 784        // feature dim
#define NK 200        // top-k
#define ND4 196       // ND / 4
#define UB 7          // bcast pipeline batch
#define RR 4          // batch rows per block (att reuse factor)
#define TPB2 512      // threads per block, kernel 2
#define TND4 (NT * ND4)   // 25088 vfloat4 per batch row

typedef float vfloat4 __attribute__((ext_vector_type(4)));

// ---------------------------------------------------------------------------
// Kernel 1 (unchanged): per-tree top-K, register-resident radix select.
// Block per tree, 256 threads; each thread owns 4 keys in VGPRs. One barrier
// per bit via [32][4] slot array. Tie-pick (lowest index first) via
// ballot+popcount ordered rank. sigmoid monotonic => top-k on raw mask bits.
// ---------------------------------------------------------------------------
__global__ __launch_bounds__(256) void topk_attention_kernel(
    const float* __restrict__ mask, float* __restrict__ att_out)
{
    __shared__ int wsum[32][4];
    __shared__ int wtie[4][4];

    const int t    = blockIdx.x;
    const int tid  = threadIdx.x;
    const int wave = tid >> 6;
    const int lane = tid & 63;

    unsigned int key[4];
    float        val[4];
    #pragma unroll
    for (int j = 0; j < 4; ++j) {
        const int d = tid + j * 256;
        if (d < ND) {
            const float f = mask[t * ND + d];
            const unsigned int b = __float_as_uint(f);
            key[j] = ((int)b < 0) ? ~b : (b | 0x80000000u);  // order-preserving
            val[j] = 1.0f / (1.0f + expf(-f));
        } else { key[j] = 0u; val[j] = 0.0f; }               // pad: never selected
    }

    unsigned int p = 0;
    int need = NK;
    for (int bit = 31; bit >= 0; --bit) {
        const unsigned int test = (p >> bit) | 1u;
        int c = 0;
        #pragma unroll
        for (int j = 0; j < 4; ++j) c += ((key[j] >> bit) == test) ? 1 : 0;
        #pragma unroll
        for (int off = 32; off > 0; off >>= 1) c += __shfl_down(c, off);
        if (lane == 0) wsum[bit][wave] = c;
        __syncthreads();
        const int tot = wsum[bit][0] + wsum[bit][1] + wsum[bit][2] + wsum[bit][3];
        if (tot >= need) p |= (1u << bit);
        else             need -= tot;
    }

    // ordered tie ranks: ascending d == ascending (j, wave, lane)
    int rankw[4];
    #pragma unroll
    for (int j = 0; j < 4; ++j) {
        const bool tie = (key[j] == p);
        const unsigned long long m = __ballot(tie);
        rankw[j] = __popcll(m & ((1ull << lane) - 1ull));
        if (lane == 0) wtie[j][wave] = __popcll(m);
    }
    __syncthreads();
    int jbase[4];
    {
        int pre = 0;
        #pragma unroll
        for (int j = 0; j < 4; ++j) {
            jbase[j] = pre;
            pre += wtie[j][0] + wtie[j][1] + wtie[j][2] + wtie[j][3];
        }
    }

    #pragma unroll
    for (int j = 0; j < 4; ++j) {
        const int d = tid + j * 256;
        if (d < ND) {
            bool keep = key[j] > p;
            if (key[j] == p) {
                int off = jbase[j] + rankw[j];
                for (int w = 0; w < 4; ++w) if (w < wave) off += wtie[j][w];
                keep = off < need;
            }
            att_out[t * ND + d] = keep ? val[j] : 0.0f;
        }
    }
}

// ---------------------------------------------------------------------------
// Kernel 2 v4: block per RR=4 batch rows (att reuse). 512 threads.
// The 4 x-rows live in LDS (784 vfloat4 = 12.5 KB); att is streamed once per
// block instead of once per row, cutting vector-memory read traffic 4x
// (822 MB total -> 514 MB). Same prefetch discipline as v3: next att batch's
// loads are issued BEFORE the current batch's stores so the load-consume
// s_waitcnt only counts loads ahead of it in the in-order vmcnt queue.
// 49 iters/thread = 7 batches of UB=7. Grid 256 blocks = 1 block/CU,
// 8 waves/CU (fills sustain 6.2 TB/s at ~10% occupancy, so this suffices).
// ---------------------------------------------------------------------------
__global__ __launch_bounds__(TPB2) void bcast_mul_kernel(
    const vfloat4* __restrict__ x4, const vfloat4* __restrict__ att4,
    vfloat4* __restrict__ out4)
{
    __shared__ vfloat4 sx[RR * ND4];          // 784 vfloat4
    const int b0  = blockIdx.x * RR;
    const int tid = threadIdx.x;

    sx[tid] = x4[(size_t)b0 * ND4 + tid];
    if (tid < RR * ND4 - TPB2)                 // 272 remaining elements
        sx[tid + TPB2] = x4[(size_t)b0 * ND4 + tid + TPB2];
    __syncthreads();

    vfloat4* __restrict__ outb = out4 + (size_t)b0 * TND4 + tid;

    vfloat4 cur[UB];
    #pragma unroll
    for (int u = 0; u < UB; ++u) cur[u] = att4[tid + u * TPB2];

    // d4 = (tid + k*512) mod 196 ; 512 mod 196 = 120
    int d4 = tid;
    if (d4 >= 2 * ND4) d4 -= 2 * ND4;
    else if (d4 >= ND4) d4 -= ND4;

    for (int nb = 0; nb < 6; ++nb) {           // batches 0..5 prefetch next
        vfloat4 nxt[UB];
        const int kb = nb * UB;
        #pragma unroll
        for (int u = 0; u < UB; ++u) nxt[u] = att4[tid + (kb + UB + u) * TPB2];
        #pragma unroll
        for (int u = 0; u < UB; ++u) {
            const int k = kb + u;
            #pragma unroll
            for (int r = 0; r < RR; ++r) {
                const vfloat4 o = cur[u] * sx[r * ND4 + d4];
                __builtin_nontemporal_store(o, &outb[(size_t)r * TND4 + k * TPB2]);
            }
            d4 += 120; if (d4 >= ND4) d4 -= ND4;
        }
        #pragma unroll
        for (int u = 0; u < UB; ++u) cur[u] = nxt[u];
    }
    // final batch (6): stores only
    #pragma unroll
    for (int u = 0; u < UB; ++u) {
        const int k = 6 * UB + u;
        #pragma unroll
        for (int r = 0; r < RR; ++r) {
            const vfloat4 o = cur[u] * sx[r * ND4 + d4];
            __builtin_nontemporal_store(o, &outb[(size_t)r * TND4 + k * TPB2]);
        }
        d4 += 120; if (d4 >= ND4) d4 -= ND4;
    }
}

extern "C" void kernel_launch(void* const* d_in, const int* in_sizes, int n_in,
                              void* d_out, int out_size, void* d_ws, size_t ws_size,
                              hipStream_t stream)
{
    (void)in_sizes; (void)n_in; (void)out_size; (void)d_ws; (void)ws_size;
    const float* x    = (const float*)d_in[0];
    const float* mask = (const float*)d_in[1];
    float* out = (float*)d_out;
    float* att = out + (size_t)NB * NT * ND;   // attention output region

    topk_attention_kernel<<<NT, 256, 0, stream>>>(mask, att);
    bcast_mul_kernel<<<NB / RR, TPB2, 0, stream>>>(
        (const vfloat4*)x, (const vfloat4*)att, (vfloat4*)out);
}